// Round 17
// baseline (1430.569 us; speedup 1.0000x reference)
//
#include <hip/hip_runtime.h>

namespace {

constexpr int kT1   = 234;
constexpr int kT    = 469;          // sequence length
constexpr int kB    = 64;
constexpr int kC    = 1024;
constexpr int kH    = 16;
constexpr int kHD   = 64;
constexpr int kM    = kB * kT;      // 30016 rows (dense)
constexpr int kTp   = 480;          // padded rows per batch for gemm0 M-space
constexpr int kMp   = kB * kTp;     // 30720 padded rows
constexpr int kVPad = 480;          // padded T for v^T layout (15 tiles of 32)
// exp2-domain: p = exp(s*0.125 + mask - 4) = exp2((s*0.125*log2e) + mask*log2e - 4*log2e)
constexpr float kC1 = 0.125f * 1.44269504089f;   // folded into q at QKV epilogue
constexpr float kC2 = 1.44269504089f;
constexpr float kShift = 4.0f * 1.44269504089f;
constexpr float kMC0 = -kShift;            // no-mask additive const (log2 domain)
constexpr float kMC1 = kC2 - kShift;       // cross-mask additive const
constexpr float kNeg = -30000.f;           // padded-key kill

typedef _Float16 f16;
typedef __fp16   fp16x2 __attribute__((ext_vector_type(2)));   // cvt_pkrtz result type
typedef _Float16 f16x8 __attribute__((ext_vector_type(8)));
typedef float    f32x4 __attribute__((ext_vector_type(4)));

__device__ __forceinline__ float fast_exp2(float x) {
#if __has_builtin(__builtin_amdgcn_exp2f)
  return __builtin_amdgcn_exp2f(x);
#else
  return __builtin_exp2f(x);
#endif
}

__device__ __forceinline__ void gload16(const void* g, void* l) {
  __builtin_amdgcn_global_load_lds(
      (const __attribute__((address_space(1))) unsigned int*)g,
      (__attribute__((address_space(3))) unsigned int*)l, 16, 0, 0);
}

// ---------------- fused prep: cast x->fp16 (480-padded rows) | transpose weights ----
// blocks [0,2048): cast; [2048,5120): Wa 1024x3072 -> WaT; [5120,6144): Wp 1024x1024
__global__ __launch_bounds__(256) void prep_kernel(
    const float* __restrict__ x, f16* __restrict__ xh,
    const float* __restrict__ Wa, f16* __restrict__ WaT,
    const float* __restrict__ Wp, f16* __restrict__ WpT, int n4) {
  __shared__ float tile[32][33];
  int b = blockIdx.x;
  if (b < 2048) {
    int i = b * blockDim.x + threadIdx.x;
    int stride = 2048 * blockDim.x;
    for (int j = i; j < n4; j += stride) {
      float4 v = reinterpret_cast<const float4*>(x)[j];
      union { f16 h[4]; unsigned long long u; } pk;
      pk.h[0] = (f16)v.x; pk.h[1] = (f16)v.y; pk.h[2] = (f16)v.z; pk.h[3] = (f16)v.w;
      int srow = j >> 8, col = j & 255;
      int bb = srow / kT;
      int drow = bb * kTp + (srow - bb * kT);
      reinterpret_cast<unsigned long long*>(xh)[drow * 256 + col] = pk.u;
    }
    return;
  }
  const float* W; f16* Wt; int N0, i;
  if (b < 5120) { W = Wa; Wt = WaT; N0 = 3072; i = b - 2048; }
  else          { W = Wp; Wt = WpT; N0 = 1024; i = b - 5120; }
  int kb = (i & 31) * 32, nb = (i >> 5) * 32;
  int tx = threadIdx.x & 31, ty = threadIdx.x >> 5;
  #pragma unroll
  for (int r = ty; r < 32; r += 8) tile[r][tx] = W[(size_t)(kb + r) * N0 + nb + tx];
  __syncthreads();
  #pragma unroll
  for (int r = ty; r < 32; r += 8) Wt[(size_t)(nb + r) * 1024 + kb + tx] = (f16)tile[tx][r];
}

// ---------------- 256x256 GEMM, 2-phase/K-tile, counted vmcnt(8), 8 waves ----------------
// EPI==0: A is the 480-row-padded xh (M'=30720); q scaled, k chunk-swizzled,
//         v written transposed/sigma-permuted/bank-swizzled via aligned 8B stores.
// EPI==1: dense A (M=30016), fp32 out.
template <int EPI>
__global__ __launch_bounds__(512, 1) void gemm256(
    const f16* __restrict__ A, const f16* __restrict__ Bt,
    const float* __restrict__ bias,
    f16* __restrict__ qh, f16* __restrict__ kh, f16* __restrict__ vh,
    float* __restrict__ outp, int nbx, int nblocks) {
  __shared__ __align__(16) f16 SH[65536];   // 128 KiB
  const int K = 1024;
  const int MA = (EPI == 0) ? kMp : kM;
  int flat = blockIdx.x;
  int swz = (flat & 7) * (nblocks >> 3) + (flat >> 3);
  int mt = swz / nbx;
  int m0 = mt * 256, n0 = (swz - mt * nbx) * 256;
  int tid = threadIdx.x;
  int wid = tid >> 6, lane = tid & 63;
  int wm = wid >> 2, wn = wid & 3;
  int lhi = lane >> 4, llo = lane & 15;

  int ci0 = tid, ci1 = tid + 512;
  int r0 = ci0 >> 2, c0 = (ci0 & 3) ^ ((r0 >> 1) & 3);
  int r1 = ci1 >> 2, c1 = (ci1 & 3) ^ ((r1 >> 1) & 3);
  int gmA0 = m0 + r0; if (gmA0 >= MA) gmA0 = MA - 1;
  int gmA1 = m0 + r1; if (gmA1 >= MA) gmA1 = MA - 1;
  const f16* aS0 = A + (size_t)gmA0 * K + c0 * 8;
  const f16* aS1 = A + (size_t)gmA1 * K + c1 * 8;
  const f16* bS0 = Bt + (size_t)(n0 + r0) * K + c0 * 8;
  const f16* bS1 = Bt + (size_t)(n0 + r1) * K + c1 * 8;
  const int ld0 = ci0 * 8, ld1 = ci1 * 8;

  auto stage = [&](int reg, int kofs) {
    gload16(aS0 + kofs, &SH[reg + ld0]);
    gload16(aS1 + kofs, &SH[reg + ld1]);
    gload16(bS0 + kofs, &SH[32768 + reg + ld0]);
    gload16(bS1 + kofs, &SH[32768 + reg + ld1]);
  };

  int aOff[8], bOff[4];
  #pragma unroll
  for (int mi = 0; mi < 8; mi++) {
    int row = wm * 128 + mi * 16 + llo;
    aOff[mi] = row * 32 + ((lhi ^ ((row >> 1) & 3)) << 3);
  }
  #pragma unroll
  for (int ni = 0; ni < 4; ni++) {
    int row = wn * 64 + ni * 16 + llo;
    bOff[ni] = row * 32 + ((lhi ^ ((row >> 1) & 3)) << 3);
  }

  const f32x4 zero4 = {0.f, 0.f, 0.f, 0.f};
  f32x4 acc[8][4];
  #pragma unroll
  for (int mi = 0; mi < 8; mi++)
    #pragma unroll
    for (int ni = 0; ni < 4; ni++) acc[mi][ni] = zero4;

  stage(0 * 8192, 0);
  stage(1 * 8192, 32);
  stage(2 * 8192, 64);
  stage(3 * 8192, 96);

  for (int t = 0; t < 16; ++t) {
    int buf = t & 1;
    // ======== phase 0 (ks = 0) ========
    if (t < 15) asm volatile("s_waitcnt vmcnt(8)" ::: "memory");
    else        asm volatile("s_waitcnt vmcnt(4)" ::: "memory");
    __builtin_amdgcn_s_barrier();
    __builtin_amdgcn_sched_barrier(0);
    {
      int rb = (buf * 2 + 0) * 8192;
      f16x8 af[8], bf[4];
      #pragma unroll
      for (int mi = 0; mi < 8; mi++)
        af[mi] = *reinterpret_cast<const f16x8*>(&SH[rb + aOff[mi]]);
      #pragma unroll
      for (int ni = 0; ni < 4; ni++)
        bf[ni] = *reinterpret_cast<const f16x8*>(&SH[32768 + rb + bOff[ni]]);
      if (t >= 1 && t <= 14)
        stage(((buf ^ 1) * 2 + 1) * 8192, (t + 1) * 64 + 32);
      asm volatile("s_waitcnt lgkmcnt(0)" ::: "memory");
      __builtin_amdgcn_sched_barrier(0);
      __builtin_amdgcn_s_setprio(1);
      #pragma unroll
      for (int mi = 0; mi < 8; mi++)
        #pragma unroll
        for (int ni = 0; ni < 4; ni++)
          acc[mi][ni] = __builtin_amdgcn_mfma_f32_16x16x32_f16(af[mi], bf[ni], acc[mi][ni], 0, 0, 0);
      __builtin_amdgcn_s_setprio(0);
    }
    // ======== phase 1 (ks = 1) ========
    if (t < 15) asm volatile("s_waitcnt vmcnt(8)" ::: "memory");
    else        asm volatile("s_waitcnt vmcnt(0)" ::: "memory");
    __builtin_amdgcn_s_barrier();
    __builtin_amdgcn_sched_barrier(0);
    {
      int rb = (buf * 2 + 1) * 8192;
      f16x8 af[8], bf[4];
      #pragma unroll
      for (int mi = 0; mi < 8; mi++)
        af[mi] = *reinterpret_cast<const f16x8*>(&SH[rb + aOff[mi]]);
      #pragma unroll
      for (int ni = 0; ni < 4; ni++)
        bf[ni] = *reinterpret_cast<const f16x8*>(&SH[32768 + rb + bOff[ni]]);
      if (t <= 13)
        stage((buf * 2 + 0) * 8192, (t + 2) * 64);
      asm volatile("s_waitcnt lgkmcnt(0)" ::: "memory");
      __builtin_amdgcn_sched_barrier(0);
      __builtin_amdgcn_s_setprio(1);
      #pragma unroll
      for (int mi = 0; mi < 8; mi++)
        #pragma unroll
        for (int ni = 0; ni < 4; ni++)
          acc[mi][ni] = __builtin_amdgcn_mfma_f32_16x16x32_f16(af[mi], bf[ni], acc[mi][ni], 0, 0, 0);
      __builtin_amdgcn_s_setprio(0);
    }
  }

  float bsv[4];
  #pragma unroll
  for (int ni = 0; ni < 4; ni++) bsv[ni] = bias[n0 + wn * 64 + ni * 16 + llo];

  if constexpr (EPI == 0) {
    const int which = n0 >> 10;
    if (which == 2) {
      // v: transposed sigma-permuted bank-swizzled write, 8B per (mi,ni).
      const int hh = ((n0 >> 6) + wn) & 15;
      #pragma unroll
      for (int mi = 0; mi < 8; mi++) {
        int row0 = m0 + wm * 128 + mi * 16 + lhi * 4;
        int bb = row0 / kTp;
        int t0 = row0 - bb * kTp;
        if (t0 < kT) {
          int lt = t0 & 31, tb = t0 & ~31;
          int plo0 = ((lt >> 4) & 1) << 2;                      // 4*t4
          int pch  = (((lt >> 3) & 1) << 1) | ((lt >> 2) & 1);  // 2*t3 + t2
          size_t vbase = (size_t)(bb * kH + hh) * kHD * kVPad;
          bool full = (t0 + 3) < kT;
          #pragma unroll
          for (int ni = 0; ni < 4; ni++) {
            int d = ni * 16 + llo;
            int touts = tb + plo0 + ((pch ^ ((d >> 1) & 3)) << 3);
            if (full) {
              union { f16 h[4]; unsigned long long u; } pk;
              pk.h[0] = (f16)(acc[mi][ni][0] + bsv[ni]);
              pk.h[1] = (f16)(acc[mi][ni][1] + bsv[ni]);
              pk.h[2] = (f16)(acc[mi][ni][2] + bsv[ni]);
              pk.h[3] = (f16)(acc[mi][ni][3] + bsv[ni]);
              *reinterpret_cast<unsigned long long*>(&vh[vbase + (size_t)d * kVPad + touts]) = pk.u;
            } else {
              #pragma unroll
              for (int rr = 0; rr < 4; rr++)
                if (t0 + rr < kT)
                  vh[vbase + (size_t)d * kVPad + touts + rr] = (f16)(acc[mi][ni][rr] + bsv[ni]);
            }
          }
        }
      }
    } else {
      f16* dst = (which == 0) ? qh : kh;
      const float osc = (which == 0) ? kC1 : 1.0f;
      #pragma unroll
      for (int mi = 0; mi < 8; mi++) {
        #pragma unroll
        for (int rr = 0; rr < 4; rr++) {
          int row = m0 + wm * 128 + mi * 16 + lhi * 4 + rr;
          int bb = row / kTp;
          int t  = row - bb * kTp;
          if (t < kT) {
            #pragma unroll
            for (int ni = 0; ni < 4; ni++) {
              int n = n0 + wn * 64 + ni * 16 + llo;
              int h = (n >> 6) & 15, d = n & 63;
              // K gets LDS-bank chunk swizzle: chunk (d>>3) stored at (d>>3)^(t&7)
              if (which == 1) d = (d & 7) | ((((d >> 3) ^ (t & 7)) & 7) << 3);
              dst[(((size_t)bb * kH + h) * kT + t) * kHD + d] =
                  (f16)((acc[mi][ni][rr] + bsv[ni]) * osc);
            }
          }
        }
      }
    }
  } else {
    #pragma unroll
    for (int mi = 0; mi < 8; mi++) {
      #pragma unroll
      for (int rr = 0; rr < 4; rr++) {
        int row = m0 + wm * 128 + mi * 16 + lhi * 4 + rr;
        if (row < kM) {
          #pragma unroll
          for (int ni = 0; ni < 4; ni++) {
            int n = n0 + wn * 64 + ni * 16 + llo;
            outp[(size_t)row * kC + n] = acc[mi][ni][rr] + bsv[ni];
          }
        }
      }
    }
  }
}

// ---------------- attention: one block per (b,h), 8 waves x 64 q-rows ----------------
// Sequential-kf softmax (16 fewer live VGPRs) + __launch_bounds__(512,4): VGPR
// capped at 128 -> 2 blocks/CU resident -> cross-block overlap hides barrier stalls.
__global__ __launch_bounds__(512, 4) void attn_kernel(
    const f16* __restrict__ qh, const f16* __restrict__ kh,
    const f16* __restrict__ vt, f16* __restrict__ y) {
  __shared__ __align__(16) f16 SH[16384];   // 4 regions x (K 2048 + V 2048 f16) = 32 KiB
  int tid = threadIdx.x;
  int w = tid >> 6, lane = tid & 63;
  int lhi = lane >> 4, llo = lane & 15;
  int bh = (blockIdx.x & 7) * 128 + (blockIdx.x >> 3);   // XCD swizzle, 1024 = 8*128
  int bb = bh >> 4, h = bh & 15;
  const f16* qb = qh + (size_t)bh * kT * kHD;
  const f16* kb = kh + (size_t)bh * kT * kHD;
  const f16* vb = vt + (size_t)bh * kHD * kVPad;
  int qbase = w * 64;

  // Q fragments (B-operand): lane holds Q[q = rf*16+llo][d = ks*32+lhi*8+j]
  f16x8 qf[4][2];
  float mA[4], mB[4];
  #pragma unroll
  for (int rf = 0; rf < 4; rf++) {
    int qr = qbase + rf * 16 + llo;
    if (qr > kT - 1) qr = kT - 1;
    #pragma unroll
    for (int ks = 0; ks < 2; ks++)
      qf[rf][ks] = *reinterpret_cast<const f16x8*>(&qb[(size_t)qr * kHD + ks * 32 + lhi * 8]);
    int q = qbase + rf * 16 + llo;
    mA[rf] = (q == 0 || q > kT1) ? kMC1 : kMC0;   // vs k in [1,234]
    mB[rf] = (q <= kT1) ? kMC1 : kMC0;            // vs k in [235,468]
  }

  // staging: waves 0-3 copy K (thread -> 16B chunk vtid), waves 4-7 copy V
  const bool isK = (tid < 256);
  const int vtid = tid & 255;
  const f16* kSrc = kb + (size_t)vtid * 8;                             // + t*2048
  const f16* vSrc = vb + (size_t)(vtid >> 2) * kVPad + (vtid & 3) * 8; // + t*32
  const int ldsK = vtid * 8;
  const int ldsV = 2048 + vtid * 8;

  int kOff[2][2], vOff[4];
  #pragma unroll
  for (int kf = 0; kf < 2; kf++)
    #pragma unroll
    for (int ks = 0; ks < 2; ks++)
      kOff[kf][ks] = (kf * 16 + llo) * 64 + (((ks * 4 + lhi) ^ (llo & 7)) << 3);
  #pragma unroll
  for (int d = 0; d < 4; d++)
    vOff[d] = 2048 + (d * 16 + llo) * 32 + ((lhi ^ ((llo >> 1) & 3)) << 3);

  const f32x4 zero4 = {0.f, 0.f, 0.f, 0.f};
  f32x4 O[4][4];
  float lp[4] = {0.f, 0.f, 0.f, 0.f};
  #pragma unroll
  for (int rf = 0; rf < 4; rf++)
    #pragma unroll
    for (int d = 0; d < 4; d++) O[rf][d] = zero4;

  auto stage = [&](int t) {
    int reg = (t & 3) * 4096;
    if (isK) gload16(kSrc + (size_t)t * 2048, &SH[reg + ldsK]);
    else     gload16(vSrc + t * 32,           &SH[reg + ldsV]);
  };

  stage(0);
  stage(1);
  stage(2);

  for (int t = 0; t < 15; ++t) {
    if (t < 13)       asm volatile("s_waitcnt vmcnt(2)" ::: "memory");
    else if (t == 13) asm volatile("s_waitcnt vmcnt(1)" ::: "memory");
    else              asm volatile("s_waitcnt vmcnt(0)" ::: "memory");
    __builtin_amdgcn_s_barrier();
    __builtin_amdgcn_sched_barrier(0);
    if (t <= 11) stage(t + 3);    // AFTER barrier: all waves done reading region (t-1)%4
    int reg = (t & 3) * 4096;
    f16x8 kfr[2][2], vfr[4];
    #pragma unroll
    for (int kf = 0; kf < 2; kf++)
      #pragma unroll
      for (int ks = 0; ks < 2; ks++)
        kfr[kf][ks] = *reinterpret_cast<const f16x8*>(&SH[reg + kOff[kf][ks]]);
    __builtin_amdgcn_sched_barrier(0);   // pin: K reads first
    #pragma unroll
    for (int d = 0; d < 4; d++)
      vfr[d] = *reinterpret_cast<const f16x8*>(&SH[reg + vOff[d]]);
    __builtin_amdgcn_sched_barrier(0);   // pin: V reads issued (still in flight)
    asm volatile("s_waitcnt lgkmcnt(4)" ::: "memory");   // K frags landed
    __builtin_amdgcn_sched_barrier(0);

    // sequential-kf: compute S-slice, exp, pack -> reuse the same 16 s-registers
    union { fp16x2 h2[4]; f16x8 v; } upa[4];
    #pragma unroll
    for (int kf = 0; kf < 2; kf++) {
      f32x4 s1[4];
      #pragma unroll
      for (int rf = 0; rf < 4; rf++) {
        float a = mA[rf], b = mB[rf];
        f32x4 sa = {a, a, a, a}, sb = {b, b, b, b};
        f32x4 sv;
        if (kf == 0) {
          if (t == 0) {                    // k==0 at (kf0, lhi0, r0): always cross
            sv = sa; if (lhi == 0) sv[0] = kMC1;
          } else if (t < 7)  sv = sa;
          else if (t == 7) {               // kf0 rows k=224+4lhi+r straddle 234
            f32x4 mix = {a, a, a, b};
            sv = (lhi <= 1) ? sa : (lhi == 2) ? mix : sb;
          } else sv = sb;
        } else {
          if (t < 7)       sv = sa;
          else if (t < 14) sv = sb;
          else {                           // kf1 rows k=464+4lhi+r: valid iff <=468
            f32x4 mix = {b, kNeg, kNeg, kNeg};
            f32x4 nng = {kNeg, kNeg, kNeg, kNeg};
            sv = (lhi == 0) ? sb : (lhi == 1) ? mix : nng;
          }
        }
        s1[rf] = sv;
      }
      __builtin_amdgcn_s_setprio(1);
      #pragma unroll
      for (int ks = 0; ks < 2; ks++)
        #pragma unroll
        for (int rf = 0; rf < 4; rf++)
          s1[rf] = __builtin_amdgcn_mfma_f32_16x16x32_f16(
              kfr[kf][ks], qf[rf][ks], s1[rf], 0, 0, 0);
      __builtin_amdgcn_s_setprio(0);
      #pragma unroll
      for (int rf = 0; rf < 4; rf++) {
        float p0 = fast_exp2(s1[rf][0]), p1 = fast_exp2(s1[rf][1]);
        float p2 = fast_exp2(s1[rf][2]), p3 = fast_exp2(s1[rf][3]);
        lp[rf] += (p0 + p1) + (p2 + p3);
        upa[rf].h2[kf * 2 + 0] = __builtin_amdgcn_cvt_pkrtz(p0, p1);
        upa[rf].h2[kf * 2 + 1] = __builtin_amdgcn_cvt_pkrtz(p2, p3);
      }
    }

    asm volatile("s_waitcnt lgkmcnt(0)" ::: "memory");   // V frags landed
    __builtin_amdgcn_sched_barrier(0);
    __builtin_amdgcn_s_setprio(1);
    #pragma unroll
    for (int d = 0; d < 4; d++)
      #pragma unroll
      for (int rf = 0; rf < 4; rf++)
        O[rf][d] = __builtin_amdgcn_mfma_f32_16x16x32_f16(upa[rf].v, vfr[d], O[rf][d], 0, 0, 0);
    __builtin_amdgcn_s_setprio(0);
  }

  // ---- row-sum reduce + redistribute + store ----
  #pragma unroll
  for (int rf = 0; rf < 4; rf++) {
    float l = lp[rf];
    l += __shfl_xor(l, 16, 64);
    l += __shfl_xor(l, 32, 64);     // all lanes: sum for q = rf*16 + llo
    #pragma unroll
    for (int r = 0; r < 4; r++) {
      float lr = __shfl(l, lhi * 4 + r, 64);   // sum for q-row lhi*4+r
      int qi = qbase + rf * 16 + lhi * 4 + r;
      if (qi < kT) {
        float inv = 1.0f / lr;
        size_t base = ((size_t)bb * kT + qi) * kC + h * kHD;
        #pragma unroll
        for (int d = 0; d < 4; d++)
          y[base + d * 16 + llo] = (f16)(O[rf][d][r] * inv);
      }
    }
  }
}

}  // namespace

extern "C" void kernel_launch(void* const* d_in, const int* in_sizes, int n_in,
                              void* d_out, int out_size, void* d_ws, size_t ws_size,
                              hipStream_t stream) {
  const float* x  = (const float*)d_in[0];
  const float* Wa = (const float*)d_in[1];
  const float* ba = (const float*)d_in[2];
  const float* Wp = (const float*)d_in[3];
  const float* bp = (const float*)d_in[4];
  float* out = (float*)d_out;
  char* ws = (char*)d_ws;

  const size_t sz_xh = (size_t)kMp * kC * 2;                // 62.9 MB (padded x_h / y_h)
  const size_t sz_wa = (size_t)3072 * 1024 * 2;             // 6.3 MB
  const size_t sz_wp = (size_t)1024 * 1024 * 2;             // 2.1 MB
  const size_t sz_q  = (size_t)kB * kH * kT * kHD * 2;      // 61.5 MB

  f16* xh  = (f16*)(ws);
  f16* WaT = (f16*)(ws + sz_xh);
  f16* WpT = (f16*)(ws + sz_xh + sz_wa);
  f16* qh  = (f16*)(ws + sz_xh + sz_wa + sz_wp);
  f16* kh2 = (f16*)(ws + sz_xh + sz_wa + sz_wp + sz_q);
  f16* vtt = (f16*)(ws + sz_xh + sz_wa + sz_wp + 2 * sz_q); // [bh][64][480], 62.9 MB
  f16* yh  = xh;                 // x_h region reused for attention output (dense 469 rows)

  prep_kernel<<<6144, 256, 0, stream>>>(x, xh, Wa, WaT, Wp, WpT, kM * kC / 4);
  gemm256<0><<<120 * 12, 512, 0, stream>>>(xh, WaT, ba, qh, kh2, vtt, nullptr, 12, 120 * 12);
  attn_kernel<<<kB * kH, 512, 0, stream>>>(qh, kh2, vtt, yh);
  gemm256<1><<<118 * 4, 512, 0, stream>>>(yh, WpT, bp, nullptr, nullptr, nullptr, out, 4, 118 * 4);
}

// Round 18
// 450.025 us; speedup vs baseline: 3.1789x; 3.1789x over previous
//
#include <hip/hip_runtime.h>

namespace {

constexpr int kT1   = 234;
constexpr int kT    = 469;          // sequence length
constexpr int kB    = 64;
constexpr int kC    = 1024;
constexpr int kH    = 16;
constexpr int kHD   = 64;
constexpr int kM    = kB * kT;      // 30016 rows (dense)
constexpr int kTp   = 480;          // padded rows per batch for gemm0 M-space
constexpr int kMp   = kB * kTp;     // 30720 padded rows
constexpr int kVPad = 480;          // padded T for v^T layout (15 tiles of 32)
// exp2-domain: p = exp(s*0.125 + mask - 4) = exp2((s*0.125*log2e) + mask*log2e - 4*log2e)
constexpr float kC1 = 0.125f * 1.44269504089f;   // folded into q at QKV epilogue
constexpr float kC2 = 1.44269504089f;
constexpr float kShift = 4.0f * 1.44269504089f;
constexpr float kMC0 = -kShift;            // no-mask additive const (log2 domain)
constexpr float kMC1 = kC2 - kShift;       // cross-mask additive const
constexpr float kNeg = -30000.f;           // padded-key kill

typedef _Float16 f16;
typedef __fp16   fp16x2 __attribute__((ext_vector_type(2)));   // cvt_pkrtz result type
typedef _Float16 f16x8 __attribute__((ext_vector_type(8)));
typedef float    f32x4 __attribute__((ext_vector_type(4)));

__device__ __forceinline__ float fast_exp2(float x) {
#if __has_builtin(__builtin_amdgcn_exp2f)
  return __builtin_amdgcn_exp2f(x);
#else
  return __builtin_exp2f(x);
#endif
}

__device__ __forceinline__ void gload16(const void* g, void* l) {
  __builtin_amdgcn_global_load_lds(
      (const __attribute__((address_space(1))) unsigned int*)g,
      (__attribute__((address_space(3))) unsigned int*)l, 16, 0, 0);
}

// ---------------- fused prep: cast x->fp16 (480-padded rows) | transpose weights ----
// blocks [0,2048): cast; [2048,5120): Wa 1024x3072 -> WaT; [5120,6144): Wp 1024x1024
__global__ __launch_bounds__(256) void prep_kernel(
    const float* __restrict__ x, f16* __restrict__ xh,
    const float* __restrict__ Wa, f16* __restrict__ WaT,
    const float* __restrict__ Wp, f16* __restrict__ WpT, int n4) {
  __shared__ float tile[32][33];
  int b = blockIdx.x;
  if (b < 2048) {
    int i = b * blockDim.x + threadIdx.x;
    int stride = 2048 * blockDim.x;
    for (int j = i; j < n4; j += stride) {
      float4 v = reinterpret_cast<const float4*>(x)[j];
      union { f16 h[4]; unsigned long long u; } pk;
      pk.h[0] = (f16)v.x; pk.h[1] = (f16)v.y; pk.h[2] = (f16)v.z; pk.h[3] = (f16)v.w;
      int srow = j >> 8, col = j & 255;
      int bb = srow / kT;
      int drow = bb * kTp + (srow - bb * kT);
      reinterpret_cast<unsigned long long*>(xh)[drow * 256 + col] = pk.u;
    }
    return;
  }
  const float* W; f16* Wt; int N0, i;
  if (b < 5120) { W = Wa; Wt = WaT; N0 = 3072; i = b - 2048; }
  else          { W = Wp; Wt = WpT; N0 = 1024; i = b - 5120; }
  int kb = (i & 31) * 32, nb = (i >> 5) * 32;
  int tx = threadIdx.x & 31, ty = threadIdx.x >> 5;
  #pragma unroll
  for (int r = ty; r < 32; r += 8) tile[r][tx] = W[(size_t)(kb + r) * N0 + nb + tx];
  __syncthreads();
  #pragma unroll
  for (int r = ty; r < 32; r += 8) Wt[(size_t)(nb + r) * 1024 + kb + tx] = (f16)tile[tx][r];
}

// ---------------- 256x256 GEMM, 2-phase/K-tile, counted vmcnt(8), 8 waves ----------------
// EPI==0: A is the 480-row-padded xh (M'=30720); q scaled, k chunk-swizzled,
//         v written transposed/sigma-permuted/bank-swizzled via aligned 8B stores.
// EPI==1: dense A (M=30016), fp32 out.
template <int EPI>
__global__ __launch_bounds__(512, 1) void gemm256(
    const f16* __restrict__ A, const f16* __restrict__ Bt,
    const float* __restrict__ bias,
    f16* __restrict__ qh, f16* __restrict__ kh, f16* __restrict__ vh,
    float* __restrict__ outp, int nbx, int nblocks) {
  __shared__ __align__(16) f16 SH[65536];   // 128 KiB
  const int K = 1024;
  const int MA = (EPI == 0) ? kMp : kM;
  int flat = blockIdx.x;
  int swz = (flat & 7) * (nblocks >> 3) + (flat >> 3);
  int mt = swz / nbx;
  int m0 = mt * 256, n0 = (swz - mt * nbx) * 256;
  int tid = threadIdx.x;
  int wid = tid >> 6, lane = tid & 63;
  int wm = wid >> 2, wn = wid & 3;
  int lhi = lane >> 4, llo = lane & 15;

  int ci0 = tid, ci1 = tid + 512;
  int r0 = ci0 >> 2, c0 = (ci0 & 3) ^ ((r0 >> 1) & 3);
  int r1 = ci1 >> 2, c1 = (ci1 & 3) ^ ((r1 >> 1) & 3);
  int gmA0 = m0 + r0; if (gmA0 >= MA) gmA0 = MA - 1;
  int gmA1 = m0 + r1; if (gmA1 >= MA) gmA1 = MA - 1;
  const f16* aS0 = A + (size_t)gmA0 * K + c0 * 8;
  const f16* aS1 = A + (size_t)gmA1 * K + c1 * 8;
  const f16* bS0 = Bt + (size_t)(n0 + r0) * K + c0 * 8;
  const f16* bS1 = Bt + (size_t)(n0 + r1) * K + c1 * 8;
  const int ld0 = ci0 * 8, ld1 = ci1 * 8;

  auto stage = [&](int reg, int kofs) {
    gload16(aS0 + kofs, &SH[reg + ld0]);
    gload16(aS1 + kofs, &SH[reg + ld1]);
    gload16(bS0 + kofs, &SH[32768 + reg + ld0]);
    gload16(bS1 + kofs, &SH[32768 + reg + ld1]);
  };

  int aOff[8], bOff[4];
  #pragma unroll
  for (int mi = 0; mi < 8; mi++) {
    int row = wm * 128 + mi * 16 + llo;
    aOff[mi] = row * 32 + ((lhi ^ ((row >> 1) & 3)) << 3);
  }
  #pragma unroll
  for (int ni = 0; ni < 4; ni++) {
    int row = wn * 64 + ni * 16 + llo;
    bOff[ni] = row * 32 + ((lhi ^ ((row >> 1) & 3)) << 3);
  }

  const f32x4 zero4 = {0.f, 0.f, 0.f, 0.f};
  f32x4 acc[8][4];
  #pragma unroll
  for (int mi = 0; mi < 8; mi++)
    #pragma unroll
    for (int ni = 0; ni < 4; ni++) acc[mi][ni] = zero4;

  stage(0 * 8192, 0);
  stage(1 * 8192, 32);
  stage(2 * 8192, 64);
  stage(3 * 8192, 96);

  for (int t = 0; t < 16; ++t) {
    int buf = t & 1;
    // ======== phase 0 (ks = 0) ========
    if (t < 15) asm volatile("s_waitcnt vmcnt(8)" ::: "memory");
    else        asm volatile("s_waitcnt vmcnt(4)" ::: "memory");
    __builtin_amdgcn_s_barrier();
    __builtin_amdgcn_sched_barrier(0);
    {
      int rb = (buf * 2 + 0) * 8192;
      f16x8 af[8], bf[4];
      #pragma unroll
      for (int mi = 0; mi < 8; mi++)
        af[mi] = *reinterpret_cast<const f16x8*>(&SH[rb + aOff[mi]]);
      #pragma unroll
      for (int ni = 0; ni < 4; ni++)
        bf[ni] = *reinterpret_cast<const f16x8*>(&SH[32768 + rb + bOff[ni]]);
      if (t >= 1 && t <= 14)
        stage(((buf ^ 1) * 2 + 1) * 8192, (t + 1) * 64 + 32);
      asm volatile("s_waitcnt lgkmcnt(0)" ::: "memory");
      __builtin_amdgcn_sched_barrier(0);
      __builtin_amdgcn_s_setprio(1);
      #pragma unroll
      for (int mi = 0; mi < 8; mi++)
        #pragma unroll
        for (int ni = 0; ni < 4; ni++)
          acc[mi][ni] = __builtin_amdgcn_mfma_f32_16x16x32_f16(af[mi], bf[ni], acc[mi][ni], 0, 0, 0);
      __builtin_amdgcn_s_setprio(0);
    }
    // ======== phase 1 (ks = 1) ========
    if (t < 15) asm volatile("s_waitcnt vmcnt(8)" ::: "memory");
    else        asm volatile("s_waitcnt vmcnt(0)" ::: "memory");
    __builtin_amdgcn_s_barrier();
    __builtin_amdgcn_sched_barrier(0);
    {
      int rb = (buf * 2 + 1) * 8192;
      f16x8 af[8], bf[4];
      #pragma unroll
      for (int mi = 0; mi < 8; mi++)
        af[mi] = *reinterpret_cast<const f16x8*>(&SH[rb + aOff[mi]]);
      #pragma unroll
      for (int ni = 0; ni < 4; ni++)
        bf[ni] = *reinterpret_cast<const f16x8*>(&SH[32768 + rb + bOff[ni]]);
      if (t <= 13)
        stage((buf * 2 + 0) * 8192, (t + 2) * 64);
      asm volatile("s_waitcnt lgkmcnt(0)" ::: "memory");
      __builtin_amdgcn_sched_barrier(0);
      __builtin_amdgcn_s_setprio(1);
      #pragma unroll
      for (int mi = 0; mi < 8; mi++)
        #pragma unroll
        for (int ni = 0; ni < 4; ni++)
          acc[mi][ni] = __builtin_amdgcn_mfma_f32_16x16x32_f16(af[mi], bf[ni], acc[mi][ni], 0, 0, 0);
      __builtin_amdgcn_s_setprio(0);
    }
  }

  float bsv[4];
  #pragma unroll
  for (int ni = 0; ni < 4; ni++) bsv[ni] = bias[n0 + wn * 64 + ni * 16 + llo];

  if constexpr (EPI == 0) {
    const int which = n0 >> 10;
    if (which == 2) {
      // v: transposed sigma-permuted bank-swizzled write, 8B per (mi,ni).
      const int hh = ((n0 >> 6) + wn) & 15;
      #pragma unroll
      for (int mi = 0; mi < 8; mi++) {
        int row0 = m0 + wm * 128 + mi * 16 + lhi * 4;
        int bb = row0 / kTp;
        int t0 = row0 - bb * kTp;
        if (t0 < kT) {
          int lt = t0 & 31, tb = t0 & ~31;
          int plo0 = ((lt >> 4) & 1) << 2;                      // 4*t4
          int pch  = (((lt >> 3) & 1) << 1) | ((lt >> 2) & 1);  // 2*t3 + t2
          size_t vbase = (size_t)(bb * kH + hh) * kHD * kVPad;
          bool full = (t0 + 3) < kT;
          #pragma unroll
          for (int ni = 0; ni < 4; ni++) {
            int d = ni * 16 + llo;
            int touts = tb + plo0 + ((pch ^ ((d >> 1) & 3)) << 3);
            if (full) {
              union { f16 h[4]; unsigned long long u; } pk;
              pk.h[0] = (f16)(acc[mi][ni][0] + bsv[ni]);
              pk.h[1] = (f16)(acc[mi][ni][1] + bsv[ni]);
              pk.h[2] = (f16)(acc[mi][ni][2] + bsv[ni]);
              pk.h[3] = (f16)(acc[mi][ni][3] + bsv[ni]);
              *reinterpret_cast<unsigned long long*>(&vh[vbase + (size_t)d * kVPad + touts]) = pk.u;
            } else {
              #pragma unroll
              for (int rr = 0; rr < 4; rr++)
                if (t0 + rr < kT)
                  vh[vbase + (size_t)d * kVPad + touts + rr] = (f16)(acc[mi][ni][rr] + bsv[ni]);
            }
          }
        }
      }
    } else {
      f16* dst = (which == 0) ? qh : kh;
      const float osc = (which == 0) ? kC1 : 1.0f;
      #pragma unroll
      for (int mi = 0; mi < 8; mi++) {
        #pragma unroll
        for (int rr = 0; rr < 4; rr++) {
          int row = m0 + wm * 128 + mi * 16 + lhi * 4 + rr;
          int bb = row / kTp;
          int t  = row - bb * kTp;
          if (t < kT) {
            #pragma unroll
            for (int ni = 0; ni < 4; ni++) {
              int n = n0 + wn * 64 + ni * 16 + llo;
              int h = (n >> 6) & 15, d = n & 63;
              // K gets LDS-bank chunk swizzle: chunk (d>>3) stored at (d>>3)^(t&7)
              if (which == 1) d = (d & 7) | ((((d >> 3) ^ (t & 7)) & 7) << 3);
              dst[(((size_t)bb * kH + h) * kT + t) * kHD + d] =
                  (f16)((acc[mi][ni][rr] + bsv[ni]) * osc);
            }
          }
        }
      }
    }
  } else {
    #pragma unroll
    for (int mi = 0; mi < 8; mi++) {
      #pragma unroll
      for (int rr = 0; rr < 4; rr++) {
        int row = m0 + wm * 128 + mi * 16 + lhi * 4 + rr;
        if (row < kM) {
          #pragma unroll
          for (int ni = 0; ni < 4; ni++) {
            int n = n0 + wn * 64 + ni * 16 + llo;
            outp[(size_t)row * kC + n] = acc[mi][ni][rr] + bsv[ni];
          }
        }
      }
    }
  }
}

// ---------------- attention: one block per (b,h), 8 waves x 64 q-rows ----------------
// Sequential-kf softmax (smaller live set); NO waves-per-EU floor (the R17 cap
// forced VGPR=64 and spilled catastrophically). If natural VGPR <= 128 the HW
// schedules 2 blocks/CU on its own.
__global__ __launch_bounds__(512) void attn_kernel(
    const f16* __restrict__ qh, const f16* __restrict__ kh,
    const f16* __restrict__ vt, f16* __restrict__ y) {
  __shared__ __align__(16) f16 SH[16384];   // 4 regions x (K 2048 + V 2048 f16) = 32 KiB
  int tid = threadIdx.x;
  int w = tid >> 6, lane = tid & 63;
  int lhi = lane >> 4, llo = lane & 15;
  int bh = (blockIdx.x & 7) * 128 + (blockIdx.x >> 3);   // XCD swizzle, 1024 = 8*128
  int bb = bh >> 4, h = bh & 15;
  const f16* qb = qh + (size_t)bh * kT * kHD;
  const f16* kb = kh + (size_t)bh * kT * kHD;
  const f16* vb = vt + (size_t)bh * kHD * kVPad;
  int qbase = w * 64;

  // Q fragments (B-operand): lane holds Q[q = rf*16+llo][d = ks*32+lhi*8+j]
  f16x8 qf[4][2];
  float mA[4], mB[4];
  #pragma unroll
  for (int rf = 0; rf < 4; rf++) {
    int qr = qbase + rf * 16 + llo;
    if (qr > kT - 1) qr = kT - 1;
    #pragma unroll
    for (int ks = 0; ks < 2; ks++)
      qf[rf][ks] = *reinterpret_cast<const f16x8*>(&qb[(size_t)qr * kHD + ks * 32 + lhi * 8]);
    int q = qbase + rf * 16 + llo;
    mA[rf] = (q == 0 || q > kT1) ? kMC1 : kMC0;   // vs k in [1,234]
    mB[rf] = (q <= kT1) ? kMC1 : kMC0;            // vs k in [235,468]
  }

  // staging: waves 0-3 copy K (thread -> 16B chunk vtid), waves 4-7 copy V
  const bool isK = (tid < 256);
  const int vtid = tid & 255;
  const f16* kSrc = kb + (size_t)vtid * 8;                             // + t*2048
  const f16* vSrc = vb + (size_t)(vtid >> 2) * kVPad + (vtid & 3) * 8; // + t*32
  const int ldsK = vtid * 8;
  const int ldsV = 2048 + vtid * 8;

  int kOff[2][2], vOff[4];
  #pragma unroll
  for (int kf = 0; kf < 2; kf++)
    #pragma unroll
    for (int ks = 0; ks < 2; ks++)
      kOff[kf][ks] = (kf * 16 + llo) * 64 + (((ks * 4 + lhi) ^ (llo & 7)) << 3);
  #pragma unroll
  for (int d = 0; d < 4; d++)
    vOff[d] = 2048 + (d * 16 + llo) * 32 + ((lhi ^ ((llo >> 1) & 3)) << 3);

  const f32x4 zero4 = {0.f, 0.f, 0.f, 0.f};
  f32x4 O[4][4];
  float lp[4] = {0.f, 0.f, 0.f, 0.f};
  #pragma unroll
  for (int rf = 0; rf < 4; rf++)
    #pragma unroll
    for (int d = 0; d < 4; d++) O[rf][d] = zero4;

  auto stage = [&](int t) {
    int reg = (t & 3) * 4096;
    if (isK) gload16(kSrc + (size_t)t * 2048, &SH[reg + ldsK]);
    else     gload16(vSrc + t * 32,           &SH[reg + ldsV]);
  };

  stage(0);
  stage(1);
  stage(2);

  for (int t = 0; t < 15; ++t) {
    if (t < 13)       asm volatile("s_waitcnt vmcnt(2)" ::: "memory");
    else if (t == 13) asm volatile("s_waitcnt vmcnt(1)" ::: "memory");
    else              asm volatile("s_waitcnt vmcnt(0)" ::: "memory");
    __builtin_amdgcn_s_barrier();
    __builtin_amdgcn_sched_barrier(0);
    if (t <= 11) stage(t + 3);    // AFTER barrier: all waves done reading region (t-1)%4
    int reg = (t & 3) * 4096;
    f16x8 kfr[2][2], vfr[4];
    #pragma unroll
    for (int kf = 0; kf < 2; kf++)
      #pragma unroll
      for (int ks = 0; ks < 2; ks++)
        kfr[kf][ks] = *reinterpret_cast<const f16x8*>(&SH[reg + kOff[kf][ks]]);
    __builtin_amdgcn_sched_barrier(0);   // pin: K reads first
    #pragma unroll
    for (int d = 0; d < 4; d++)
      vfr[d] = *reinterpret_cast<const f16x8*>(&SH[reg + vOff[d]]);
    __builtin_amdgcn_sched_barrier(0);   // pin: V reads issued (still in flight)
    asm volatile("s_waitcnt lgkmcnt(4)" ::: "memory");   // K frags landed
    __builtin_amdgcn_sched_barrier(0);

    // sequential-kf: compute S-slice, exp, pack -> reuse the same 16 s-registers
    union { fp16x2 h2[4]; f16x8 v; } upa[4];
    #pragma unroll
    for (int kf = 0; kf < 2; kf++) {
      f32x4 s1[4];
      #pragma unroll
      for (int rf = 0; rf < 4; rf++) {
        float a = mA[rf], b = mB[rf];
        f32x4 sa = {a, a, a, a}, sb = {b, b, b, b};
        f32x4 sv;
        if (kf == 0) {
          if (t == 0) {                    // k==0 at (kf0, lhi0, r0): always cross
            sv = sa; if (lhi == 0) sv[0] = kMC1;
          } else if (t < 7)  sv = sa;
          else if (t == 7) {               // kf0 rows k=224+4lhi+r straddle 234
            f32x4 mix = {a, a, a, b};
            sv = (lhi <= 1) ? sa : (lhi == 2) ? mix : sb;
          } else sv = sb;
        } else {
          if (t < 7)       sv = sa;
          else if (t < 14) sv = sb;
          else {                           // kf1 rows k=464+4lhi+r: valid iff <=468
            f32x4 mix = {b, kNeg, kNeg, kNeg};
            f32x4 nng = {kNeg, kNeg, kNeg, kNeg};
            sv = (lhi == 0) ? sb : (lhi == 1) ? mix : nng;
          }
        }
        s1[rf] = sv;
      }
      __builtin_amdgcn_s_setprio(1);
      #pragma unroll
      for (int ks = 0; ks < 2; ks++)
        #pragma unroll
        for (int rf = 0; rf < 4; rf++)
          s1[rf] = __builtin_amdgcn_mfma_f32_16x16x32_f16(
              kfr[kf][ks], qf[rf][ks], s1[rf], 0, 0, 0);
      __builtin_amdgcn_s_setprio(0);
      #pragma unroll
      for (int rf = 0; rf < 4; rf++) {
        float p0 = fast_exp2(s1[rf][0]), p1 = fast_exp2(s1[rf][1]);
        float p2 = fast_exp2(s1[rf][2]), p3 = fast_exp2(s1[rf][3]);
        lp[rf] += (p0 + p1) + (p2 + p3);
        upa[rf].h2[kf * 2 + 0] = __builtin_amdgcn_cvt_pkrtz(p0, p1);
        upa[rf].h2[kf * 2 + 1] = __builtin_amdgcn_cvt_pkrtz(p2, p3);
      }
    }

    asm volatile("s_waitcnt lgkmcnt(0)" ::: "memory");   // V frags landed
    __builtin_amdgcn_sched_barrier(0);
    __builtin_amdgcn_s_setprio(1);
    #pragma unroll
    for (int d = 0; d < 4; d++)
      #pragma unroll
      for (int rf = 0; rf < 4; rf++)
        O[rf][d] = __builtin_amdgcn_mfma_f32_16x16x32_f16(upa[rf].v, vfr[d], O[rf][d], 0, 0, 0);
    __builtin_amdgcn_s_setprio(0);
  }

  // ---- row-sum reduce + redistribute + store ----
  #pragma unroll
  for (int rf = 0; rf < 4; rf++) {
    float l = lp[rf];
    l += __shfl_xor(l, 16, 64);
    l += __shfl_xor(l, 32, 64);     // all lanes: sum for q = rf*16 + llo
    #pragma unroll
    for (int r = 0; r < 4; r++) {
      float lr = __shfl(l, lhi * 4 + r, 64);   // sum for q-row lhi*4+r
      int qi = qbase + rf * 16 + lhi * 4 + r;
      if (qi < kT) {
        float inv = 1.0f / lr;
        size_t base = ((size_t)bb * kT + qi) * kC + h * kHD;
        #pragma unroll
        for (int d = 0; d < 4; d++)
          y[base + d * 16 + llo] = (f16)(O[rf][d][r] * inv);
      }
    }
  }
}

}  // namespace

extern "C" void kernel_launch(void* const* d_in, const int* in_sizes, int n_in,
                              void* d_out, int out_size, void* d_ws, size_t ws_size,
                              hipStream_t stream) {
  const float* x  = (const float*)d_in[0];
  const float* Wa = (const float*)d_in[1];
  const float* ba = (const float*)d_in[2];
  const float* Wp = (const float*)d_in[3];
  const float* bp = (const float*)d_in[4];
  float* out = (float*)d_out;
  char* ws = (char*)d_ws;

  const size_t sz_xh = (size_t)kMp * kC * 2;                // 62.9 MB (padded x_h / y_h)
  const size_t sz_wa = (size_t)3072 * 1024 * 2;             // 6.3 MB
  const size_t sz_wp = (size_t)1024 * 1024 * 2;             // 2.1 MB
  const size_t sz_q  = (size_t)kB * kH * kT * kHD * 2;      // 61.5 MB

  f16* xh  = (f16*)(ws);
  f16* WaT = (f16*)(ws + sz_xh);
  f16* WpT = (f16*)(ws + sz_xh + sz_wa);
  f16* qh  = (f16*)(ws + sz_xh + sz_wa + sz_wp);
  f16* kh2 = (f16*)(ws + sz_xh + sz_wa + sz_wp + sz_q);
  f16* vtt = (f16*)(ws + sz_xh + sz_wa + sz_wp + 2 * sz_q); // [bh][64][480], 62.9 MB
  f16* yh  = xh;                 // x_h region reused for attention output (dense 469 rows)

  prep_kernel<<<6144, 256, 0, stream>>>(x, xh, Wa, WaT, Wp, WpT, kM * kC / 4);
  gemm256<0><<<120 * 12, 512, 0, stream>>>(xh, WaT, ba, qh, kh2, vtt, nullptr, 12, 120 * 12);
  attn_kernel<<<kB * kH, 512, 0, stream>>>(qh, kh2, vtt, yh);
  gemm256<1><<<118 * 4, 512, 0, stream>>>(yh, WpT, bp, nullptr, nullptr, nullptr, out, 4, 118 * 4);
}

// Round 19
// 447.201 us; speedup vs baseline: 3.1989x; 1.0063x over previous
//
#include <hip/hip_runtime.h>

namespace {

constexpr int kT1   = 234;
constexpr int kT    = 469;          // sequence length
constexpr int kB    = 64;
constexpr int kC    = 1024;
constexpr int kH    = 16;
constexpr int kHD   = 64;
constexpr int kM    = kB * kT;      // 30016 rows (dense)
constexpr int kTp   = 480;          // padded rows per batch for gemm0 M-space
constexpr int kMp   = kB * kTp;     // 30720 padded rows
constexpr int kVPad = 480;          // padded T for v^T layout (15 tiles of 32)
// exp2-domain: p = exp(s*0.125 + mask - 4) = exp2((s*0.125*log2e) + mask*log2e - 4*log2e)
constexpr float kC1 = 0.125f * 1.44269504089f;   // folded into q at QKV epilogue
constexpr float kC2 = 1.44269504089f;
constexpr float kShift = 4.0f * 1.44269504089f;
constexpr float kMC0 = -kShift;            // no-mask additive const (log2 domain)
constexpr float kMC1 = kC2 - kShift;       // cross-mask additive const
constexpr float kNeg = -30000.f;           // padded-key kill

typedef _Float16 f16;
typedef __fp16   fp16x2 __attribute__((ext_vector_type(2)));   // cvt_pkrtz result type
typedef _Float16 f16x8 __attribute__((ext_vector_type(8)));
typedef float    f32x4 __attribute__((ext_vector_type(4)));

__device__ __forceinline__ float fast_exp2(float x) {
#if __has_builtin(__builtin_amdgcn_exp2f)
  return __builtin_amdgcn_exp2f(x);
#else
  return __builtin_exp2f(x);
#endif
}

__device__ __forceinline__ void gload16(const void* g, void* l) {
  __builtin_amdgcn_global_load_lds(
      (const __attribute__((address_space(1))) unsigned int*)g,
      (__attribute__((address_space(3))) unsigned int*)l, 16, 0, 0);
}

// ---------------- fused prep: cast x->fp16 (480-padded rows) | transpose weights ----
// blocks [0,2048): cast; [2048,5120): Wa 1024x3072 -> WaT; [5120,6144): Wp 1024x1024
__global__ __launch_bounds__(256) void prep_kernel(
    const float* __restrict__ x, f16* __restrict__ xh,
    const float* __restrict__ Wa, f16* __restrict__ WaT,
    const float* __restrict__ Wp, f16* __restrict__ WpT, int n4) {
  __shared__ float tile[32][33];
  int b = blockIdx.x;
  if (b < 2048) {
    int i = b * blockDim.x + threadIdx.x;
    int stride = 2048 * blockDim.x;
    for (int j = i; j < n4; j += stride) {
      float4 v = reinterpret_cast<const float4*>(x)[j];
      union { f16 h[4]; unsigned long long u; } pk;
      pk.h[0] = (f16)v.x; pk.h[1] = (f16)v.y; pk.h[2] = (f16)v.z; pk.h[3] = (f16)v.w;
      int srow = j >> 8, col = j & 255;
      int bb = srow / kT;
      int drow = bb * kTp + (srow - bb * kT);
      reinterpret_cast<unsigned long long*>(xh)[drow * 256 + col] = pk.u;
    }
    return;
  }
  const float* W; f16* Wt; int N0, i;
  if (b < 5120) { W = Wa; Wt = WaT; N0 = 3072; i = b - 2048; }
  else          { W = Wp; Wt = WpT; N0 = 1024; i = b - 5120; }
  int kb = (i & 31) * 32, nb = (i >> 5) * 32;
  int tx = threadIdx.x & 31, ty = threadIdx.x >> 5;
  #pragma unroll
  for (int r = ty; r < 32; r += 8) tile[r][tx] = W[(size_t)(kb + r) * N0 + nb + tx];
  __syncthreads();
  #pragma unroll
  for (int r = ty; r < 32; r += 8) Wt[(size_t)(nb + r) * 1024 + kb + tx] = (f16)tile[tx][r];
}

// ---------------- 256x256 GEMM, 2-phase/K-tile, counted vmcnt(8), 8 waves ----------------
// EPI==0: A is the 480-row-padded xh (M'=30720); q scaled, k chunk-swizzled,
//         v written transposed/sigma-permuted/bank-swizzled via aligned 8B stores.
// EPI==1: dense A (M=30016), fp32 out.
template <int EPI>
__global__ __launch_bounds__(512, 1) void gemm256(
    const f16* __restrict__ A, const f16* __restrict__ Bt,
    const float* __restrict__ bias,
    f16* __restrict__ qh, f16* __restrict__ kh, f16* __restrict__ vh,
    float* __restrict__ outp, int nbx, int nblocks) {
  __shared__ __align__(16) f16 SH[65536];   // 128 KiB
  const int K = 1024;
  const int MA = (EPI == 0) ? kMp : kM;
  int flat = blockIdx.x;
  int swz = (flat & 7) * (nblocks >> 3) + (flat >> 3);
  int mt = swz / nbx;
  int m0 = mt * 256, n0 = (swz - mt * nbx) * 256;
  int tid = threadIdx.x;
  int wid = tid >> 6, lane = tid & 63;
  int wm = wid >> 2, wn = wid & 3;
  int lhi = lane >> 4, llo = lane & 15;

  int ci0 = tid, ci1 = tid + 512;
  int r0 = ci0 >> 2, c0 = (ci0 & 3) ^ ((r0 >> 1) & 3);
  int r1 = ci1 >> 2, c1 = (ci1 & 3) ^ ((r1 >> 1) & 3);
  int gmA0 = m0 + r0; if (gmA0 >= MA) gmA0 = MA - 1;
  int gmA1 = m0 + r1; if (gmA1 >= MA) gmA1 = MA - 1;
  const f16* aS0 = A + (size_t)gmA0 * K + c0 * 8;
  const f16* aS1 = A + (size_t)gmA1 * K + c1 * 8;
  const f16* bS0 = Bt + (size_t)(n0 + r0) * K + c0 * 8;
  const f16* bS1 = Bt + (size_t)(n0 + r1) * K + c1 * 8;
  const int ld0 = ci0 * 8, ld1 = ci1 * 8;

  auto stage = [&](int reg, int kofs) {
    gload16(aS0 + kofs, &SH[reg + ld0]);
    gload16(aS1 + kofs, &SH[reg + ld1]);
    gload16(bS0 + kofs, &SH[32768 + reg + ld0]);
    gload16(bS1 + kofs, &SH[32768 + reg + ld1]);
  };

  int aOff[8], bOff[4];
  #pragma unroll
  for (int mi = 0; mi < 8; mi++) {
    int row = wm * 128 + mi * 16 + llo;
    aOff[mi] = row * 32 + ((lhi ^ ((row >> 1) & 3)) << 3);
  }
  #pragma unroll
  for (int ni = 0; ni < 4; ni++) {
    int row = wn * 64 + ni * 16 + llo;
    bOff[ni] = row * 32 + ((lhi ^ ((row >> 1) & 3)) << 3);
  }

  const f32x4 zero4 = {0.f, 0.f, 0.f, 0.f};
  f32x4 acc[8][4];
  #pragma unroll
  for (int mi = 0; mi < 8; mi++)
    #pragma unroll
    for (int ni = 0; ni < 4; ni++) acc[mi][ni] = zero4;

  stage(0 * 8192, 0);
  stage(1 * 8192, 32);
  stage(2 * 8192, 64);
  stage(3 * 8192, 96);

  for (int t = 0; t < 16; ++t) {
    int buf = t & 1;
    // ======== phase 0 (ks = 0) ========
    if (t < 15) asm volatile("s_waitcnt vmcnt(8)" ::: "memory");
    else        asm volatile("s_waitcnt vmcnt(4)" ::: "memory");
    __builtin_amdgcn_s_barrier();
    __builtin_amdgcn_sched_barrier(0);
    {
      int rb = (buf * 2 + 0) * 8192;
      f16x8 af[8], bf[4];
      #pragma unroll
      for (int mi = 0; mi < 8; mi++)
        af[mi] = *reinterpret_cast<const f16x8*>(&SH[rb + aOff[mi]]);
      #pragma unroll
      for (int ni = 0; ni < 4; ni++)
        bf[ni] = *reinterpret_cast<const f16x8*>(&SH[32768 + rb + bOff[ni]]);
      if (t >= 1 && t <= 14)
        stage(((buf ^ 1) * 2 + 1) * 8192, (t + 1) * 64 + 32);
      asm volatile("s_waitcnt lgkmcnt(0)" ::: "memory");
      __builtin_amdgcn_sched_barrier(0);
      __builtin_amdgcn_s_setprio(1);
      #pragma unroll
      for (int mi = 0; mi < 8; mi++)
        #pragma unroll
        for (int ni = 0; ni < 4; ni++)
          acc[mi][ni] = __builtin_amdgcn_mfma_f32_16x16x32_f16(af[mi], bf[ni], acc[mi][ni], 0, 0, 0);
      __builtin_amdgcn_s_setprio(0);
    }
    // ======== phase 1 (ks = 1) ========
    if (t < 15) asm volatile("s_waitcnt vmcnt(8)" ::: "memory");
    else        asm volatile("s_waitcnt vmcnt(0)" ::: "memory");
    __builtin_amdgcn_s_barrier();
    __builtin_amdgcn_sched_barrier(0);
    {
      int rb = (buf * 2 + 1) * 8192;
      f16x8 af[8], bf[4];
      #pragma unroll
      for (int mi = 0; mi < 8; mi++)
        af[mi] = *reinterpret_cast<const f16x8*>(&SH[rb + aOff[mi]]);
      #pragma unroll
      for (int ni = 0; ni < 4; ni++)
        bf[ni] = *reinterpret_cast<const f16x8*>(&SH[32768 + rb + bOff[ni]]);
      if (t <= 13)
        stage((buf * 2 + 0) * 8192, (t + 2) * 64);
      asm volatile("s_waitcnt lgkmcnt(0)" ::: "memory");
      __builtin_amdgcn_sched_barrier(0);
      __builtin_amdgcn_s_setprio(1);
      #pragma unroll
      for (int mi = 0; mi < 8; mi++)
        #pragma unroll
        for (int ni = 0; ni < 4; ni++)
          acc[mi][ni] = __builtin_amdgcn_mfma_f32_16x16x32_f16(af[mi], bf[ni], acc[mi][ni], 0, 0, 0);
      __builtin_amdgcn_s_setprio(0);
    }
  }

  float bsv[4];
  #pragma unroll
  for (int ni = 0; ni < 4; ni++) bsv[ni] = bias[n0 + wn * 64 + ni * 16 + llo];

  if constexpr (EPI == 0) {
    const int which = n0 >> 10;
    if (which == 2) {
      // v: transposed sigma-permuted bank-swizzled write, 8B per (mi,ni).
      const int hh = ((n0 >> 6) + wn) & 15;
      #pragma unroll
      for (int mi = 0; mi < 8; mi++) {
        int row0 = m0 + wm * 128 + mi * 16 + lhi * 4;
        int bb = row0 / kTp;
        int t0 = row0 - bb * kTp;
        if (t0 < kT) {
          int lt = t0 & 31, tb = t0 & ~31;
          int plo0 = ((lt >> 4) & 1) << 2;                      // 4*t4
          int pch  = (((lt >> 3) & 1) << 1) | ((lt >> 2) & 1);  // 2*t3 + t2
          size_t vbase = (size_t)(bb * kH + hh) * kHD * kVPad;
          bool full = (t0 + 3) < kT;
          #pragma unroll
          for (int ni = 0; ni < 4; ni++) {
            int d = ni * 16 + llo;
            int touts = tb + plo0 + ((pch ^ ((d >> 1) & 3)) << 3);
            if (full) {
              union { f16 h[4]; unsigned long long u; } pk;
              pk.h[0] = (f16)(acc[mi][ni][0] + bsv[ni]);
              pk.h[1] = (f16)(acc[mi][ni][1] + bsv[ni]);
              pk.h[2] = (f16)(acc[mi][ni][2] + bsv[ni]);
              pk.h[3] = (f16)(acc[mi][ni][3] + bsv[ni]);
              *reinterpret_cast<unsigned long long*>(&vh[vbase + (size_t)d * kVPad + touts]) = pk.u;
            } else {
              #pragma unroll
              for (int rr = 0; rr < 4; rr++)
                if (t0 + rr < kT)
                  vh[vbase + (size_t)d * kVPad + touts + rr] = (f16)(acc[mi][ni][rr] + bsv[ni]);
            }
          }
        }
      }
    } else {
      f16* dst = (which == 0) ? qh : kh;
      const float osc = (which == 0) ? kC1 : 1.0f;
      #pragma unroll
      for (int mi = 0; mi < 8; mi++) {
        #pragma unroll
        for (int rr = 0; rr < 4; rr++) {
          int row = m0 + wm * 128 + mi * 16 + lhi * 4 + rr;
          int bb = row / kTp;
          int t  = row - bb * kTp;
          if (t < kT) {
            #pragma unroll
            for (int ni = 0; ni < 4; ni++) {
              int n = n0 + wn * 64 + ni * 16 + llo;
              int h = (n >> 6) & 15, d = n & 63;
              // K gets LDS-bank chunk swizzle: chunk (d>>3) stored at (d>>3)^(t&7)
              if (which == 1) d = (d & 7) | ((((d >> 3) ^ (t & 7)) & 7) << 3);
              dst[(((size_t)bb * kH + h) * kT + t) * kHD + d] =
                  (f16)((acc[mi][ni][rr] + bsv[ni]) * osc);
            }
          }
        }
      }
    }
  } else {
    #pragma unroll
    for (int mi = 0; mi < 8; mi++) {
      #pragma unroll
      for (int rr = 0; rr < 4; rr++) {
        int row = m0 + wm * 128 + mi * 16 + lhi * 4 + rr;
        if (row < kM) {
          #pragma unroll
          for (int ni = 0; ni < 4; ni++) {
            int n = n0 + wn * 64 + ni * 16 + llo;
            outp[(size_t)row * kC + n] = acc[mi][ni][rr] + bsv[ni];
          }
        }
      }
    }
  }
}

// ---------------- attention: one block per (b,h), 8 waves x 64 q-rows ----------------
// Minimal-sync variant: keep only the mandatory vmcnt (gload_lds completion is
// invisible to the compiler) + barriers; drop all sched_barrier pins and manual
// lgkm waits -- the compiler's dataflow tracking inserts fine-grained lgkmcnt
// before each dependent MFMA and can interleave exp2/MFMA across kf slices.
__global__ __launch_bounds__(512) void attn_kernel(
    const f16* __restrict__ qh, const f16* __restrict__ kh,
    const f16* __restrict__ vt, f16* __restrict__ y) {
  __shared__ __align__(16) f16 SH[16384];   // 4 regions x (K 2048 + V 2048 f16) = 32 KiB
  int tid = threadIdx.x;
  int w = tid >> 6, lane = tid & 63;
  int lhi = lane >> 4, llo = lane & 15;
  int bh = (blockIdx.x & 7) * 128 + (blockIdx.x >> 3);   // XCD swizzle, 1024 = 8*128
  int bb = bh >> 4, h = bh & 15;
  const f16* qb = qh + (size_t)bh * kT * kHD;
  const f16* kb = kh + (size_t)bh * kT * kHD;
  const f16* vb = vt + (size_t)bh * kHD * kVPad;
  int qbase = w * 64;

  // Q fragments (B-operand): lane holds Q[q = rf*16+llo][d = ks*32+lhi*8+j]
  f16x8 qf[4][2];
  float mA[4], mB[4];
  #pragma unroll
  for (int rf = 0; rf < 4; rf++) {
    int qr = qbase + rf * 16 + llo;
    if (qr > kT - 1) qr = kT - 1;
    #pragma unroll
    for (int ks = 0; ks < 2; ks++)
      qf[rf][ks] = *reinterpret_cast<const f16x8*>(&qb[(size_t)qr * kHD + ks * 32 + lhi * 8]);
    int q = qbase + rf * 16 + llo;
    mA[rf] = (q == 0 || q > kT1) ? kMC1 : kMC0;   // vs k in [1,234]
    mB[rf] = (q <= kT1) ? kMC1 : kMC0;            // vs k in [235,468]
  }

  // staging: waves 0-3 copy K (thread -> 16B chunk vtid), waves 4-7 copy V
  const bool isK = (tid < 256);
  const int vtid = tid & 255;
  const f16* kSrc = kb + (size_t)vtid * 8;                             // + t*2048
  const f16* vSrc = vb + (size_t)(vtid >> 2) * kVPad + (vtid & 3) * 8; // + t*32
  const int ldsK = vtid * 8;
  const int ldsV = 2048 + vtid * 8;

  int kOff[2][2], vOff[4];
  #pragma unroll
  for (int kf = 0; kf < 2; kf++)
    #pragma unroll
    for (int ks = 0; ks < 2; ks++)
      kOff[kf][ks] = (kf * 16 + llo) * 64 + (((ks * 4 + lhi) ^ (llo & 7)) << 3);
  #pragma unroll
  for (int d = 0; d < 4; d++)
    vOff[d] = 2048 + (d * 16 + llo) * 32 + ((lhi ^ ((llo >> 1) & 3)) << 3);

  const f32x4 zero4 = {0.f, 0.f, 0.f, 0.f};
  f32x4 O[4][4];
  float lp[4] = {0.f, 0.f, 0.f, 0.f};
  #pragma unroll
  for (int rf = 0; rf < 4; rf++)
    #pragma unroll
    for (int d = 0; d < 4; d++) O[rf][d] = zero4;

  auto stage = [&](int t) {
    int reg = (t & 3) * 4096;
    if (isK) gload16(kSrc + (size_t)t * 2048, &SH[reg + ldsK]);
    else     gload16(vSrc + t * 32,           &SH[reg + ldsV]);
  };

  stage(0);
  stage(1);
  stage(2);

  for (int t = 0; t < 15; ++t) {
    if (t < 13)       asm volatile("s_waitcnt vmcnt(2)" ::: "memory");
    else if (t == 13) asm volatile("s_waitcnt vmcnt(1)" ::: "memory");
    else              asm volatile("s_waitcnt vmcnt(0)" ::: "memory");
    __builtin_amdgcn_s_barrier();
    if (t <= 11) stage(t + 3);    // AFTER barrier: all waves done reading region (t-1)%4
    int reg = (t & 3) * 4096;
    f16x8 kfr[2][2], vfr[4];
    #pragma unroll
    for (int kf = 0; kf < 2; kf++)
      #pragma unroll
      for (int ks = 0; ks < 2; ks++)
        kfr[kf][ks] = *reinterpret_cast<const f16x8*>(&SH[reg + kOff[kf][ks]]);
    #pragma unroll
    for (int d = 0; d < 4; d++)
      vfr[d] = *reinterpret_cast<const f16x8*>(&SH[reg + vOff[d]]);

    // sequential-kf: compute S-slice, exp, pack -> reuse the same 16 s-registers
    union { fp16x2 h2[4]; f16x8 v; } upa[4];
    #pragma unroll
    for (int kf = 0; kf < 2; kf++) {
      f32x4 s1[4];
      #pragma unroll
      for (int rf = 0; rf < 4; rf++) {
        float a = mA[rf], b = mB[rf];
        f32x4 sa = {a, a, a, a}, sb = {b, b, b, b};
        f32x4 sv;
        if (kf == 0) {
          if (t == 0) {                    // k==0 at (kf0, lhi0, r0): always cross
            sv = sa; if (lhi == 0) sv[0] = kMC1;
          } else if (t < 7)  sv = sa;
          else if (t == 7) {               // kf0 rows k=224+4lhi+r straddle 234
            f32x4 mix = {a, a, a, b};
            sv = (lhi <= 1) ? sa : (lhi == 2) ? mix : sb;
          } else sv = sb;
        } else {
          if (t < 7)       sv = sa;
          else if (t < 14) sv = sb;
          else {                           // kf1 rows k=464+4lhi+r: valid iff <=468
            f32x4 mix = {b, kNeg, kNeg, kNeg};
            f32x4 nng = {kNeg, kNeg, kNeg, kNeg};
            sv = (lhi == 0) ? sb : (lhi == 1) ? mix : nng;
          }
        }
        s1[rf] = sv;
      }
      __builtin_amdgcn_s_setprio(1);
      #pragma unroll
      for (int ks = 0; ks < 2; ks++)
        #pragma unroll
        for (int rf = 0; rf < 4; rf++)
          s1[rf] = __builtin_amdgcn_mfma_f32_16x16x32_f16(
              kfr[kf][ks], qf[rf][ks], s1[rf], 0, 0, 0);
      __builtin_amdgcn_s_setprio(0);
      #pragma unroll
      for (int rf = 0; rf < 4; rf++) {
        float p0 = fast_exp2(s1[rf][0]), p1 = fast_exp2(s1[rf][1]);
        float p2 = fast_exp2(s1[rf][2]), p3 = fast_exp2(s1[rf][3]);
        lp[rf] += (p0 + p1) + (p2 + p3);
        upa[rf].h2[kf * 2 + 0] = __builtin_amdgcn_cvt_pkrtz(p0, p1);
        upa[rf].h2[kf * 2 + 1] = __builtin_amdgcn_cvt_pkrtz(p2, p3);
      }
    }

    __builtin_amdgcn_s_setprio(1);
    #pragma unroll
    for (int d = 0; d < 4; d++)
      #pragma unroll
      for (int rf = 0; rf < 4; rf++)
        O[rf][d] = __builtin_amdgcn_mfma_f32_16x16x32_f16(upa[rf].v, vfr[d], O[rf][d], 0, 0, 0);
    __builtin_amdgcn_s_setprio(0);
  }

  // ---- row-sum reduce + redistribute + store ----
  #pragma unroll
  for (int rf = 0; rf < 4; rf++) {
    float l = lp[rf];
    l += __shfl_xor(l, 16, 64);
    l += __shfl_xor(l, 32, 64);     // all lanes: sum for q = rf*16 + llo
    #pragma unroll
    for (int r = 0; r < 4; r++) {
      float lr = __shfl(l, lhi * 4 + r, 64);   // sum for q-row lhi*4+r
      int qi = qbase + rf * 16 + lhi * 4 + r;
      if (qi < kT) {
        float inv = 1.0f / lr;
        size_t base = ((size_t)bb * kT + qi) * kC + h * kHD;
        #pragma unroll
        for (int d = 0; d < 4; d++)
          y[base + d * 16 + llo] = (f16)(O[rf][d][r] * inv);
      }
    }
  }
}

}  // namespace

extern "C" void kernel_launch(void* const* d_in, const int* in_sizes, int n_in,
                              void* d_out, int out_size, void* d_ws, size_t ws_size,
                              hipStream_t stream) {
  const float* x  = (const float*)d_in[0];
  const float* Wa = (const float*)d_in[1];
  const float* ba = (const float*)d_in[2];
  const float* Wp = (const float*)d_in[3];
  const float* bp = (const float*)d_in[4];
  float* out = (float*)d_out;
  char* ws = (char*)d_ws;

  const size_t sz_xh = (size_t)kMp * kC * 2;                // 62.9 MB (padded x_h / y_h)
  const size_t sz_wa = (size_t)3072 * 1024 * 2;             // 6.3 MB
  const size_t sz_wp = (size_t)1024 * 1024 * 2;             // 2.1 MB
  const size_t sz_q  = (size_t)kB * kH * kT * kHD * 2;      // 61.5 MB

  f16* xh  = (f16*)(ws);
  f16* WaT = (f16*)(ws + sz_xh);
  f16* WpT = (f16*)(ws + sz_xh + sz_wa);
  f16* qh  = (f16*)(ws + sz_xh + sz_wa + sz_wp);
  f16* kh2 = (f16*)(ws + sz_xh + sz_wa + sz_wp + sz_q);
  f16* vtt = (f16*)(ws + sz_xh + sz_wa + sz_wp + 2 * sz_q); // [bh][64][480], 62.9 MB
  f16* yh  = xh;                 // x_h region reused for attention output (dense 469 rows)

  prep_kernel<<<6144, 256, 0, stream>>>(x, xh, Wa, WaT, Wp, WpT, kM * kC / 4);
  gemm256<0><<<120 * 12, 512, 0, stream>>>(xh, WaT, ba, qh, kh2, vtt, nullptr, 12, 120 * 12);
  attn_kernel<<<kB * kH, 512, 0, stream>>>(qh, kh2, vtt, yh);
  gemm256<1><<<118 * 4, 512, 0, stream>>>(yh, WpT, bp, nullptr, nullptr, nullptr, out, 4, 118 * 4);
}

// Round 20
// 440.690 us; speedup vs baseline: 3.2462x; 1.0148x over previous
//
#include <hip/hip_runtime.h>

namespace {

constexpr int kT1   = 234;
constexpr int kT    = 469;          // sequence length
constexpr int kB    = 64;
constexpr int kC    = 1024;
constexpr int kH    = 16;
constexpr int kHD   = 64;
constexpr int kM    = kB * kT;      // 30016 rows (dense)
constexpr int kTp   = 480;          // padded rows per batch for gemm0 M-space
constexpr int kMp   = kB * kTp;     // 30720 padded rows
constexpr int kVPad = 480;          // padded T for v^T layout (15 tiles of 32)
// exp2-domain: p = exp(s*0.125 + mask - 4) = exp2((s*0.125*log2e) + mask*log2e - 4*log2e)
constexpr float kC1 = 0.125f * 1.44269504089f;   // folded into q at QKV epilogue
constexpr float kC2 = 1.44269504089f;
constexpr float kShift = 4.0f * 1.44269504089f;
constexpr float kMC0 = -kShift;            // no-mask additive const (log2 domain)
constexpr float kMC1 = kC2 - kShift;       // cross-mask additive const
constexpr float kNeg = -30000.f;           // padded-key kill

typedef _Float16 f16;
typedef __fp16   fp16x2 __attribute__((ext_vector_type(2)));   // cvt_pkrtz result type
typedef _Float16 f16x8 __attribute__((ext_vector_type(8)));
typedef float    f32x4 __attribute__((ext_vector_type(4)));

__device__ __forceinline__ float fast_exp2(float x) {
#if __has_builtin(__builtin_amdgcn_exp2f)
  return __builtin_amdgcn_exp2f(x);
#else
  return __builtin_exp2f(x);
#endif
}

__device__ __forceinline__ void gload16(const void* g, void* l) {
  __builtin_amdgcn_global_load_lds(
      (const __attribute__((address_space(1))) unsigned int*)g,
      (__attribute__((address_space(3))) unsigned int*)l, 16, 0, 0);
}

// ---------------- fused prep: cast x->fp16 (480-padded rows) | transpose weights ----
// blocks [0,2048): cast; [2048,5120): Wa 1024x3072 -> WaT; [5120,6144): Wp 1024x1024
__global__ __launch_bounds__(256) void prep_kernel(
    const float* __restrict__ x, f16* __restrict__ xh,
    const float* __restrict__ Wa, f16* __restrict__ WaT,
    const float* __restrict__ Wp, f16* __restrict__ WpT, int n4) {
  __shared__ float tile[32][33];
  int b = blockIdx.x;
  if (b < 2048) {
    int i = b * blockDim.x + threadIdx.x;
    int stride = 2048 * blockDim.x;
    for (int j = i; j < n4; j += stride) {
      float4 v = reinterpret_cast<const float4*>(x)[j];
      union { f16 h[4]; unsigned long long u; } pk;
      pk.h[0] = (f16)v.x; pk.h[1] = (f16)v.y; pk.h[2] = (f16)v.z; pk.h[3] = (f16)v.w;
      int srow = j >> 8, col = j & 255;
      int bb = srow / kT;
      int drow = bb * kTp + (srow - bb * kT);
      reinterpret_cast<unsigned long long*>(xh)[drow * 256 + col] = pk.u;
    }
    return;
  }
  const float* W; f16* Wt; int N0, i;
  if (b < 5120) { W = Wa; Wt = WaT; N0 = 3072; i = b - 2048; }
  else          { W = Wp; Wt = WpT; N0 = 1024; i = b - 5120; }
  int kb = (i & 31) * 32, nb = (i >> 5) * 32;
  int tx = threadIdx.x & 31, ty = threadIdx.x >> 5;
  #pragma unroll
  for (int r = ty; r < 32; r += 8) tile[r][tx] = W[(size_t)(kb + r) * N0 + nb + tx];
  __syncthreads();
  #pragma unroll
  for (int r = ty; r < 32; r += 8) Wt[(size_t)(nb + r) * 1024 + kb + tx] = (f16)tile[tx][r];
}

// ---------------- 256x256 GEMM, 2-phase/K-tile, counted vmcnt(8), 8 waves ----------------
// No manual lgkm drain before MFMA: the compiler's fine-grained lgkmcnt lets MFMAs
// start as soon as their fragments land. WAR is safe: every phase's ds_reads are
// consumed by that phase's MFMAs (RAW waits retire them) before the next barrier.
// EPI==0: A is the 480-row-padded xh; q scaled, k chunk-swizzled, v transposed.
// EPI==1: dense A (M=30016), fp32 out.
template <int EPI>
__global__ __launch_bounds__(512, 1) void gemm256(
    const f16* __restrict__ A, const f16* __restrict__ Bt,
    const float* __restrict__ bias,
    f16* __restrict__ qh, f16* __restrict__ kh, f16* __restrict__ vh,
    float* __restrict__ outp, int nbx, int nblocks) {
  __shared__ __align__(16) f16 SH[65536];   // 128 KiB
  const int K = 1024;
  const int MA = (EPI == 0) ? kMp : kM;
  int flat = blockIdx.x;
  int swz = (flat & 7) * (nblocks >> 3) + (flat >> 3);
  int mt = swz / nbx;
  int m0 = mt * 256, n0 = (swz - mt * nbx) * 256;
  int tid = threadIdx.x;
  int wid = tid >> 6, lane = tid & 63;
  int wm = wid >> 2, wn = wid & 3;
  int lhi = lane >> 4, llo = lane & 15;

  int ci0 = tid, ci1 = tid + 512;
  int r0 = ci0 >> 2, c0 = (ci0 & 3) ^ ((r0 >> 1) & 3);
  int r1 = ci1 >> 2, c1 = (ci1 & 3) ^ ((r1 >> 1) & 3);
  int gmA0 = m0 + r0; if (gmA0 >= MA) gmA0 = MA - 1;
  int gmA1 = m0 + r1; if (gmA1 >= MA) gmA1 = MA - 1;
  const f16* aS0 = A + (size_t)gmA0 * K + c0 * 8;
  const f16* aS1 = A + (size_t)gmA1 * K + c1 * 8;
  const f16* bS0 = Bt + (size_t)(n0 + r0) * K + c0 * 8;
  const f16* bS1 = Bt + (size_t)(n0 + r1) * K + c1 * 8;
  const int ld0 = ci0 * 8, ld1 = ci1 * 8;

  auto stage = [&](int reg, int kofs) {
    gload16(aS0 + kofs, &SH[reg + ld0]);
    gload16(aS1 + kofs, &SH[reg + ld1]);
    gload16(bS0 + kofs, &SH[32768 + reg + ld0]);
    gload16(bS1 + kofs, &SH[32768 + reg + ld1]);
  };

  int aOff[8], bOff[4];
  #pragma unroll
  for (int mi = 0; mi < 8; mi++) {
    int row = wm * 128 + mi * 16 + llo;
    aOff[mi] = row * 32 + ((lhi ^ ((row >> 1) & 3)) << 3);
  }
  #pragma unroll
  for (int ni = 0; ni < 4; ni++) {
    int row = wn * 64 + ni * 16 + llo;
    bOff[ni] = row * 32 + ((lhi ^ ((row >> 1) & 3)) << 3);
  }

  const f32x4 zero4 = {0.f, 0.f, 0.f, 0.f};
  f32x4 acc[8][4];
  #pragma unroll
  for (int mi = 0; mi < 8; mi++)
    #pragma unroll
    for (int ni = 0; ni < 4; ni++) acc[mi][ni] = zero4;

  stage(0 * 8192, 0);
  stage(1 * 8192, 32);
  stage(2 * 8192, 64);
  stage(3 * 8192, 96);

  for (int t = 0; t < 16; ++t) {
    int buf = t & 1;
    // ======== phase 0 (ks = 0) ========
    if (t < 15) asm volatile("s_waitcnt vmcnt(8)" ::: "memory");
    else        asm volatile("s_waitcnt vmcnt(4)" ::: "memory");
    __builtin_amdgcn_s_barrier();
    __builtin_amdgcn_sched_barrier(0);
    {
      int rb = (buf * 2 + 0) * 8192;
      f16x8 af[8], bf[4];
      #pragma unroll
      for (int mi = 0; mi < 8; mi++)
        af[mi] = *reinterpret_cast<const f16x8*>(&SH[rb + aOff[mi]]);
      #pragma unroll
      for (int ni = 0; ni < 4; ni++)
        bf[ni] = *reinterpret_cast<const f16x8*>(&SH[32768 + rb + bOff[ni]]);
      if (t >= 1 && t <= 14)
        stage(((buf ^ 1) * 2 + 1) * 8192, (t + 1) * 64 + 32);
      __builtin_amdgcn_s_setprio(1);
      #pragma unroll
      for (int mi = 0; mi < 8; mi++)
        #pragma unroll
        for (int ni = 0; ni < 4; ni++)
          acc[mi][ni] = __builtin_amdgcn_mfma_f32_16x16x32_f16(af[mi], bf[ni], acc[mi][ni], 0, 0, 0);
      __builtin_amdgcn_s_setprio(0);
    }
    // ======== phase 1 (ks = 1) ========
    if (t < 15) asm volatile("s_waitcnt vmcnt(8)" ::: "memory");
    else        asm volatile("s_waitcnt vmcnt(0)" ::: "memory");
    __builtin_amdgcn_s_barrier();
    __builtin_amdgcn_sched_barrier(0);
    {
      int rb = (buf * 2 + 1) * 8192;
      f16x8 af[8], bf[4];
      #pragma unroll
      for (int mi = 0; mi < 8; mi++)
        af[mi] = *reinterpret_cast<const f16x8*>(&SH[rb + aOff[mi]]);
      #pragma unroll
      for (int ni = 0; ni < 4; ni++)
        bf[ni] = *reinterpret_cast<const f16x8*>(&SH[32768 + rb + bOff[ni]]);
      if (t <= 13)
        stage((buf * 2 + 0) * 8192, (t + 2) * 64);
      __builtin_amdgcn_s_setprio(1);
      #pragma unroll
      for (int mi = 0; mi < 8; mi++)
        #pragma unroll
        for (int ni = 0; ni < 4; ni++)
          acc[mi][ni] = __builtin_amdgcn_mfma_f32_16x16x32_f16(af[mi], bf[ni], acc[mi][ni], 0, 0, 0);
      __builtin_amdgcn_s_setprio(0);
    }
  }

  float bsv[4];
  #pragma unroll
  for (int ni = 0; ni < 4; ni++) bsv[ni] = bias[n0 + wn * 64 + ni * 16 + llo];

  if constexpr (EPI == 0) {
    const int which = n0 >> 10;
    if (which == 2) {
      // v: transposed sigma-permuted bank-swizzled write, 8B per (mi,ni).
      const int hh = ((n0 >> 6) + wn) & 15;
      #pragma unroll
      for (int mi = 0; mi < 8; mi++) {
        int row0 = m0 + wm * 128 + mi * 16 + lhi * 4;
        int bb = row0 / kTp;
        int t0 = row0 - bb * kTp;
        if (t0 < kT) {
          int lt = t0 & 31, tb = t0 & ~31;
          int plo0 = ((lt >> 4) & 1) << 2;                      // 4*t4
          int pch  = (((lt >> 3) & 1) << 1) | ((lt >> 2) & 1);  // 2*t3 + t2
          size_t vbase = (size_t)(bb * kH + hh) * kHD * kVPad;
          bool full = (t0 + 3) < kT;
          #pragma unroll
          for (int ni = 0; ni < 4; ni++) {
            int d = ni * 16 + llo;
            int touts = tb + plo0 + ((pch ^ ((d >> 1) & 3)) << 3);
            if (full) {
              union { f16 h[4]; unsigned long long u; } pk;
              pk.h[0] = (f16)(acc[mi][ni][0] + bsv[ni]);
              pk.h[1] = (f16)(acc[mi][ni][1] + bsv[ni]);
              pk.h[2] = (f16)(acc[mi][ni][2] + bsv[ni]);
              pk.h[3] = (f16)(acc[mi][ni][3] + bsv[ni]);
              *reinterpret_cast<unsigned long long*>(&vh[vbase + (size_t)d * kVPad + touts]) = pk.u;
            } else {
              #pragma unroll
              for (int rr = 0; rr < 4; rr++)
                if (t0 + rr < kT)
                  vh[vbase + (size_t)d * kVPad + touts + rr] = (f16)(acc[mi][ni][rr] + bsv[ni]);
            }
          }
        }
      }
    } else {
      f16* dst = (which == 0) ? qh : kh;
      const float osc = (which == 0) ? kC1 : 1.0f;
      #pragma unroll
      for (int mi = 0; mi < 8; mi++) {
        #pragma unroll
        for (int rr = 0; rr < 4; rr++) {
          int row = m0 + wm * 128 + mi * 16 + lhi * 4 + rr;
          int bb = row / kTp;
          int t  = row - bb * kTp;
          if (t < kT) {
            #pragma unroll
            for (int ni = 0; ni < 4; ni++) {
              int n = n0 + wn * 64 + ni * 16 + llo;
              int h = (n >> 6) & 15, d = n & 63;
              // K gets LDS-bank chunk swizzle: chunk (d>>3) stored at (d>>3)^(t&7)
              if (which == 1) d = (d & 7) | ((((d >> 3) ^ (t & 7)) & 7) << 3);
              dst[(((size_t)bb * kH + h) * kT + t) * kHD + d] =
                  (f16)((acc[mi][ni][rr] + bsv[ni]) * osc);
            }
          }
        }
      }
    }
  } else {
    #pragma unroll
    for (int mi = 0; mi < 8; mi++) {
      #pragma unroll
      for (int rr = 0; rr < 4; rr++) {
        int row = m0 + wm * 128 + mi * 16 + lhi * 4 + rr;
        if (row < kM) {
          #pragma unroll
          for (int ni = 0; ni < 4; ni++) {
            int n = n0 + wn * 64 + ni * 16 + llo;
            outp[(size_t)row * kC + n] = acc[mi][ni][rr] + bsv[ni];
          }
        }
      }
    }
  }
}

// ---------------- attention: one block per (b,h), 8 waves x 64 q-rows ----------------
// Minimal-sync variant (round-19 verified): mandatory vmcnt + barriers only.
__global__ __launch_bounds__(512) void attn_kernel(
    const f16* __restrict__ qh, const f16* __restrict__ kh,
    const f16* __restrict__ vt, f16* __restrict__ y) {
  __shared__ __align__(16) f16 SH[16384];   // 4 regions x (K 2048 + V 2048 f16) = 32 KiB
  int tid = threadIdx.x;
  int w = tid >> 6, lane = tid & 63;
  int lhi = lane >> 4, llo = lane & 15;
  int bh = (blockIdx.x & 7) * 128 + (blockIdx.x >> 3);   // XCD swizzle, 1024 = 8*128
  int bb = bh >> 4, h = bh & 15;
  const f16* qb = qh + (size_t)bh * kT * kHD;
  const f16* kb = kh + (size_t)bh * kT * kHD;
  const f16* vb = vt + (size_t)bh * kHD * kVPad;
  int qbase = w * 64;

  // Q fragments (B-operand): lane holds Q[q = rf*16+llo][d = ks*32+lhi*8+j]
  f16x8 qf[4][2];
  float mA[4], mB[4];
  #pragma unroll
  for (int rf = 0; rf < 4; rf++) {
    int qr = qbase + rf * 16 + llo;
    if (qr > kT - 1) qr = kT - 1;
    #pragma unroll
    for (int ks = 0; ks < 2; ks++)
      qf[rf][ks] = *reinterpret_cast<const f16x8*>(&qb[(size_t)qr * kHD + ks * 32 + lhi * 8]);
    int q = qbase + rf * 16 + llo;
    mA[rf] = (q == 0 || q > kT1) ? kMC1 : kMC0;   // vs k in [1,234]
    mB[rf] = (q <= kT1) ? kMC1 : kMC0;            // vs k in [235,468]
  }

  // staging: waves 0-3 copy K (thread -> 16B chunk vtid), waves 4-7 copy V
  const bool isK = (tid < 256);
  const int vtid = tid & 255;
  const f16* kSrc = kb + (size_t)vtid * 8;                             // + t*2048
  const f16* vSrc = vb + (size_t)(vtid >> 2) * kVPad + (vtid & 3) * 8; // + t*32
  const int ldsK = vtid * 8;
  const int ldsV = 2048 + vtid * 8;

  int kOff[2][2], vOff[4];
  #pragma unroll
  for (int kf = 0; kf < 2; kf++)
    #pragma unroll
    for (int ks = 0; ks < 2; ks++)
      kOff[kf][ks] = (kf * 16 + llo) * 64 + (((ks * 4 + lhi) ^ (llo & 7)) << 3);
  #pragma unroll
  for (int d = 0; d < 4; d++)
    vOff[d] = 2048 + (d * 16 + llo) * 32 + ((lhi ^ ((llo >> 1) & 3)) << 3);

  const f32x4 zero4 = {0.f, 0.f, 0.f, 0.f};
  f32x4 O[4][4];
  float lp[4] = {0.f, 0.f, 0.f, 0.f};
  #pragma unroll
  for (int rf = 0; rf < 4; rf++)
    #pragma unroll
    for (int d = 0; d < 4; d++) O[rf][d] = zero4;

  auto stage = [&](int t) {
    int reg = (t & 3) * 4096;
    if (isK) gload16(kSrc + (size_t)t * 2048, &SH[reg + ldsK]);
    else     gload16(vSrc + t * 32,           &SH[reg + ldsV]);
  };

  stage(0);
  stage(1);
  stage(2);

  for (int t = 0; t < 15; ++t) {
    if (t < 13)       asm volatile("s_waitcnt vmcnt(2)" ::: "memory");
    else if (t == 13) asm volatile("s_waitcnt vmcnt(1)" ::: "memory");
    else              asm volatile("s_waitcnt vmcnt(0)" ::: "memory");
    __builtin_amdgcn_s_barrier();
    if (t <= 11) stage(t + 3);    // AFTER barrier: all waves done reading region (t-1)%4
    int reg = (t & 3) * 4096;
    f16x8 kfr[2][2], vfr[4];
    #pragma unroll
    for (int kf = 0; kf < 2; kf++)
      #pragma unroll
      for (int ks = 0; ks < 2; ks++)
        kfr[kf][ks] = *reinterpret_cast<const f16x8*>(&SH[reg + kOff[kf][ks]]);
    #pragma unroll
    for (int d = 0; d < 4; d++)
      vfr[d] = *reinterpret_cast<const f16x8*>(&SH[reg + vOff[d]]);

    // sequential-kf: compute S-slice, exp, pack -> reuse the same 16 s-registers
    union { fp16x2 h2[4]; f16x8 v; } upa[4];
    #pragma unroll
    for (int kf = 0; kf < 2; kf++) {
      f32x4 s1[4];
      #pragma unroll
      for (int rf = 0; rf < 4; rf++) {
        float a = mA[rf], b = mB[rf];
        f32x4 sa = {a, a, a, a}, sb = {b, b, b, b};
        f32x4 sv;
        if (kf == 0) {
          if (t == 0) {                    // k==0 at (kf0, lhi0, r0): always cross
            sv = sa; if (lhi == 0) sv[0] = kMC1;
          } else if (t < 7)  sv = sa;
          else if (t == 7) {               // kf0 rows k=224+4lhi+r straddle 234
            f32x4 mix = {a, a, a, b};
            sv = (lhi <= 1) ? sa : (lhi == 2) ? mix : sb;
          } else sv = sb;
        } else {
          if (t < 7)       sv = sa;
          else if (t < 14) sv = sb;
          else {                           // kf1 rows k=464+4lhi+r: valid iff <=468
            f32x4 mix = {b, kNeg, kNeg, kNeg};
            f32x4 nng = {kNeg, kNeg, kNeg, kNeg};
            sv = (lhi == 0) ? sb : (lhi == 1) ? mix : nng;
          }
        }
        s1[rf] = sv;
      }
      __builtin_amdgcn_s_setprio(1);
      #pragma unroll
      for (int ks = 0; ks < 2; ks++)
        #pragma unroll
        for (int rf = 0; rf < 4; rf++)
          s1[rf] = __builtin_amdgcn_mfma_f32_16x16x32_f16(
              kfr[kf][ks], qf[rf][ks], s1[rf], 0, 0, 0);
      __builtin_amdgcn_s_setprio(0);
      #pragma unroll
      for (int rf = 0; rf < 4; rf++) {
        float p0 = fast_exp2(s1[rf][0]), p1 = fast_exp2(s1[rf][1]);
        float p2 = fast_exp2(s1[rf][2]), p3 = fast_exp2(s1[rf][3]);
        lp[rf] += (p0 + p1) + (p2 + p3);
        upa[rf].h2[kf * 2 + 0] = __builtin_amdgcn_cvt_pkrtz(p0, p1);
        upa[rf].h2[kf * 2 + 1] = __builtin_amdgcn_cvt_pkrtz(p2, p3);
      }
    }

    __builtin_amdgcn_s_setprio(1);
    #pragma unroll
    for (int d = 0; d < 4; d++)
      #pragma unroll
      for (int rf = 0; rf < 4; rf++)
        O[rf][d] = __builtin_amdgcn_mfma_f32_16x16x32_f16(upa[rf].v, vfr[d], O[rf][d], 0, 0, 0);
    __builtin_amdgcn_s_setprio(0);
  }

  // ---- row-sum reduce + redistribute + store ----
  #pragma unroll
  for (int rf = 0; rf < 4; rf++) {
    float l = lp[rf];
    l += __shfl_xor(l, 16, 64);
    l += __shfl_xor(l, 32, 64);     // all lanes: sum for q = rf*16 + llo
    #pragma unroll
    for (int r = 0; r < 4; r++) {
      float lr = __shfl(l, lhi * 4 + r, 64);   // sum for q-row lhi*4+r
      int qi = qbase + rf * 16 + lhi * 4 + r;
      if (qi < kT) {
        float inv = 1.0f / lr;
        size_t base = ((size_t)bb * kT + qi) * kC + h * kHD;
        #pragma unroll
        for (int d = 0; d < 4; d++)
          y[base + d * 16 + llo] = (f16)(O[rf][d][r] * inv);
      }
    }
  }
}

}  // namespace

extern "C" void kernel_launch(void* const* d_in, const int* in_sizes, int n_in,
                              void* d_out, int out_size, void* d_ws, size_t ws_size,
                              hipStream_t stream) {
  const float* x  = (const float*)d_in[0];
  const float* Wa = (const float*)d_in[1];
  const float* ba = (const float*)d_in[2];
  const float* Wp = (const float*)d_in[3];
  const float* bp = (const float*)d_in[4];
  float* out = (float*)d_out;
  char* ws = (char*)d_ws;

  const size_t sz_xh = (size_t)kMp * kC * 2;                // 62.9 MB (padded x_h / y_h)
  const size_t sz_wa = (size_t)3072 * 1024 * 2;             // 6.3 MB
  const size_t sz_wp = (size_t)1024 * 1024 * 2;             // 2.1 MB
  const size_t sz_q  = (size_t)kB * kH * kT * kHD * 2;      // 61.5 MB

  f16* xh  = (f16*)(ws);
  f16* WaT = (f16*)(ws + sz_xh);
  f16* WpT = (f16*)(ws + sz_xh + sz_wa);
  f16* qh  = (f16*)(ws + sz_xh + sz_wa + sz_wp);
  f16* kh2 = (f16*)(ws + sz_xh + sz_wa + sz_wp + sz_q);
  f16* vtt = (f16*)(ws + sz_xh + sz_wa + sz_wp + 2 * sz_q); // [bh][64][480], 62.9 MB
  f16* yh  = xh;                 // x_h region reused for attention output (dense 469 rows)

  prep_kernel<<<6144, 256, 0, stream>>>(x, xh, Wa, WaT, Wp, WpT, kM * kC / 4);
  gemm256<0><<<120 * 12, 512, 0, stream>>>(xh, WaT, ba, qh, kh2, vtt, nullptr, 12, 120 * 12);
  attn_kernel<<<kB * kH, 512, 0, stream>>>(qh, kh2, vtt, yh);
  gemm256<1><<<118 * 4, 512, 0, stream>>>(yh, WpT, bp, nullptr, nullptr, nullptr, out, 4, 118 * 4);
}